// Round 1
// baseline (1083.757 us; speedup 1.0000x reference)
//
#include <hip/hip_runtime.h>

#define NN 100000
#define NE 1600000
#define HD 128
#define NL 3
#define NG 1024

// ---------------- init ----------------
__global__ void k_init(int* hist, int* gstart, int* gend) {
    int i = blockIdx.x * blockDim.x + threadIdx.x;
    if (i < NN) hist[i] = 0;
    if (i < NG) { gstart[i] = 0x7fffffff; gend[i] = 0; }
}

// ---------------- degree histogram over dst ----------------
__global__ void k_hist(const int* __restrict__ dst, int* __restrict__ hist) {
    int i = blockIdx.x * blockDim.x + threadIdx.x;
    if (i < NE) atomicAdd(&hist[dst[i]], 1);
}

// ---------------- single-block exclusive scan -> rowPtr ----------------
__global__ void k_scan(const int* __restrict__ hist, int* __restrict__ rowPtr) {
    __shared__ int tmp[1024];
    int t = threadIdx.x;
    if (t == 0) rowPtr[0] = 0;
    int carry = 0;
    for (int base = 0; base < NN; base += 1024) {
        int v = (base + t < NN) ? hist[base + t] : 0;
        tmp[t] = v;
        __syncthreads();
        for (int off = 1; off < 1024; off <<= 1) {
            int u = (t >= off) ? tmp[t - off] : 0;
            __syncthreads();
            tmp[t] += u;
            __syncthreads();
        }
        if (base + t < NN) rowPtr[base + t + 1] = carry + tmp[t];
        carry += tmp[1023];
        __syncthreads();
    }
}

// ---------------- dinv + cursor init ----------------
__global__ void k_dinv(const int* __restrict__ rowPtr, float* __restrict__ dinv,
                       int* __restrict__ cursor) {
    int i = blockIdx.x * blockDim.x + threadIdx.x;
    if (i < NN) {
        int indeg = rowPtr[i + 1] - rowPtr[i];
        dinv[i] = rsqrtf((float)(indeg + 1));   // +1 self loop, always > 0
        cursor[i] = rowPtr[i];
    }
}

// ---------------- CSR fill (group edges by dst) ----------------
__global__ void k_fill(const int* __restrict__ src, const int* __restrict__ dst,
                       const float* __restrict__ dinv, int* __restrict__ cursor,
                       int* __restrict__ srcS, float* __restrict__ normS) {
    int e = blockIdx.x * blockDim.x + threadIdx.x;
    if (e < NE) {
        int s = src[e], d = dst[e];
        int pos = atomicAdd(&cursor[d], 1);
        srcS[pos]  = s;
        normS[pos] = dinv[s] * dinv[d];
    }
}

// ---------------- embedding lookup ----------------
__global__ void k_embed(const int* __restrict__ x, const float* __restrict__ emb,
                        float* __restrict__ h) {
    int i = blockIdx.x * blockDim.x + threadIdx.x;   // over NN*32 float4 slots
    if (i < NN * 32) {
        int n = i >> 5, seg = i & 31;
        const float4* s = (const float4*)(emb + (size_t)x[n] * HD);
        ((float4*)(h + (size_t)n * HD))[seg] = s[seg];
    }
}

// ---------------- GEMM: B = A @ W  (A:[NN,128], W:[128,128]) ----------------
__global__ __launch_bounds__(256) void k_gemm(const float* __restrict__ A,
                                              const float* __restrict__ W,
                                              float* __restrict__ B) {
    __shared__ float As[64][33];     // +1 pad
    __shared__ float Wl[32][128];
    int n0 = blockIdx.x * 64;
    int t = threadIdx.x;
    int cg = t & 15, rg = t >> 4;
    int c0 = cg * 8, r0 = rg * 4;
    float acc[4][8];
#pragma unroll
    for (int i = 0; i < 4; ++i)
#pragma unroll
        for (int j = 0; j < 8; ++j) acc[i][j] = 0.f;

    for (int kc = 0; kc < 4; ++kc) {
        int k0 = kc * 32;
        // stage A chunk [64][32]
#pragma unroll
        for (int it = 0; it < 2; ++it) {
            int lin = t + it * 256;
            int row = lin >> 3, seg = lin & 7;
            float4 v = make_float4(0.f, 0.f, 0.f, 0.f);
            if (n0 + row < NN)
                v = *(const float4*)(A + (size_t)(n0 + row) * HD + k0 + seg * 4);
            As[row][seg * 4 + 0] = v.x;
            As[row][seg * 4 + 1] = v.y;
            As[row][seg * 4 + 2] = v.z;
            As[row][seg * 4 + 3] = v.w;
        }
        // stage W chunk [32][128]
#pragma unroll
        for (int it = 0; it < 4; ++it) {
            int lin = t + it * 256;
            int row = lin >> 5, seg = lin & 31;
            *(float4*)(&Wl[row][seg * 4]) =
                *(const float4*)(W + (size_t)(k0 + row) * HD + seg * 4);
        }
        __syncthreads();
#pragma unroll 8
        for (int k = 0; k < 32; ++k) {
            float a0 = As[r0 + 0][k], a1 = As[r0 + 1][k];
            float a2 = As[r0 + 2][k], a3 = As[r0 + 3][k];
            float4 w0 = *(float4*)(&Wl[k][c0]);
            float4 w1 = *(float4*)(&Wl[k][c0 + 4]);
            float w[8] = {w0.x, w0.y, w0.z, w0.w, w1.x, w1.y, w1.z, w1.w};
#pragma unroll
            for (int j = 0; j < 8; ++j) {
                acc[0][j] = fmaf(a0, w[j], acc[0][j]);
                acc[1][j] = fmaf(a1, w[j], acc[1][j]);
                acc[2][j] = fmaf(a2, w[j], acc[2][j]);
                acc[3][j] = fmaf(a3, w[j], acc[3][j]);
            }
        }
        __syncthreads();
    }
#pragma unroll
    for (int i = 0; i < 4; ++i) {
        int row = n0 + r0 + i;
        if (row < NN) {
            float4 o0 = make_float4(acc[i][0], acc[i][1], acc[i][2], acc[i][3]);
            float4 o1 = make_float4(acc[i][4], acc[i][5], acc[i][6], acc[i][7]);
            *(float4*)(B + (size_t)row * HD + c0)     = o0;
            *(float4*)(B + (size_t)row * HD + c0 + 4) = o1;
        }
    }
}

// ---------------- pull-gather: A[n] = sum_e norm*B[src] + dinv^2*B[n] + b ----------------
__global__ __launch_bounds__(256) void k_gather(const float* __restrict__ B,
                                                const int* __restrict__ rowPtr,
                                                const int* __restrict__ srcS,
                                                const float* __restrict__ normS,
                                                const float* __restrict__ dinv,
                                                const float* __restrict__ bias,
                                                float* __restrict__ A, int relu) {
    int wid  = (blockIdx.x * blockDim.x + threadIdx.x) >> 6;  // wave per node
    int lane = threadIdx.x & 63;
    if (wid >= NN) return;
    int n = wid;
    float dn = dinv[n];
    float2 b0 = ((const float2*)(B + (size_t)n * HD))[lane];
    float2 acc;
    acc.x = dn * dn * b0.x;
    acc.y = dn * dn * b0.y;
    int beg = rowPtr[n], end = rowPtr[n + 1];
    for (int idx = beg; idx < end; ++idx) {
        int s   = srcS[idx];
        float w = normS[idx];
        float2 v = ((const float2*)(B + (size_t)s * HD))[lane];
        acc.x = fmaf(w, v.x, acc.x);
        acc.y = fmaf(w, v.y, acc.y);
    }
    float2 bb = ((const float2*)bias)[lane];
    acc.x += bb.x;
    acc.y += bb.y;
    if (relu) { acc.x = fmaxf(acc.x, 0.f); acc.y = fmaxf(acc.y, 0.f); }
    ((float2*)(A + (size_t)n * HD))[lane] = acc;
}

// ---------------- graph bounds (batch is sorted) ----------------
__global__ void k_bounds(const int* __restrict__ batch, int* __restrict__ gstart,
                         int* __restrict__ gend) {
    int i = blockIdx.x * blockDim.x + threadIdx.x;
    if (i < NN) {
        int g = batch[i];
        atomicMin(&gstart[g], i);
        atomicMax(&gend[g], i + 1);
    }
}

// ---------------- mean pool per graph ----------------
__global__ __launch_bounds__(128) void k_pool(const float* __restrict__ A,
                                              const int* __restrict__ gstart,
                                              const int* __restrict__ gend,
                                              float* __restrict__ out) {
    int g = blockIdx.x;
    int t = threadIdx.x;
    int s = gstart[g], e = gend[g];
    float acc = 0.f;
    int cnt = 0;
    if (s < e) {
        cnt = e - s;
        for (int n = s; n < e; ++n) acc += A[(size_t)n * HD + t];
    }
    out[(size_t)g * HD + t] = acc / fmaxf((float)cnt, 1.f);
}

extern "C" void kernel_launch(void* const* d_in, const int* in_sizes, int n_in,
                              void* d_out, int out_size, void* d_ws, size_t ws_size,
                              hipStream_t stream) {
    const int*   x     = (const int*)d_in[0];
    const int*   ei    = (const int*)d_in[1];
    const int*   batch = (const int*)d_in[2];
    const float* emb   = (const float*)d_in[3];
    const float* Ws    = (const float*)d_in[4];
    const float* bs    = (const float*)d_in[5];
    float* out = (float*)d_out;

    const int* srcE = ei;
    const int* dstE = ei + NE;

    char* ws = (char*)d_ws;
    size_t off = 0;
    auto alloc = [&](size_t bytes) {
        size_t o = off;
        off = (off + bytes + 255) & ~(size_t)255;
        return o;
    };
    float* hA     = (float*)(ws + alloc((size_t)NN * HD * 4));
    float* hB     = (float*)(ws + alloc((size_t)NN * HD * 4));
    float* dinv   = (float*)(ws + alloc((size_t)NN * 4));
    int*   rowPtr = (int*)  (ws + alloc((size_t)(NN + 1) * 4));
    int*   cursor = (int*)  (ws + alloc((size_t)NN * 4));   // also hist
    int*   srcS   = (int*)  (ws + alloc((size_t)NE * 4));
    float* normS  = (float*)(ws + alloc((size_t)NE * 4));
    int*   gstart = (int*)  (ws + alloc((size_t)NG * 4));
    int*   gend   = (int*)  (ws + alloc((size_t)NG * 4));
    (void)ws_size; (void)in_sizes; (void)n_in; (void)out_size;

    int* hist = cursor;  // reuse: hist phase then cursor phase

    k_init<<<(NN + 255) / 256, 256, 0, stream>>>(hist, gstart, gend);
    k_hist<<<(NE + 255) / 256, 256, 0, stream>>>(dstE, hist);
    k_scan<<<1, 1024, 0, stream>>>(hist, rowPtr);
    k_dinv<<<(NN + 255) / 256, 256, 0, stream>>>(rowPtr, dinv, cursor);
    k_fill<<<(NE + 255) / 256, 256, 0, stream>>>(srcE, dstE, dinv, cursor, srcS, normS);
    k_embed<<<(NN * 32 + 255) / 256, 256, 0, stream>>>(x, emb, hA);

    for (int l = 0; l < NL; ++l) {
        k_gemm<<<(NN + 63) / 64, 256, 0, stream>>>(hA, Ws + (size_t)l * HD * HD, hB);
        k_gather<<<(NN + 3) / 4, 256, 0, stream>>>(hB, rowPtr, srcS, normS, dinv,
                                                   bs + (size_t)l * HD, hA,
                                                   (l < NL - 1) ? 1 : 0);
    }

    k_bounds<<<(NN + 255) / 256, 256, 0, stream>>>(batch, gstart, gend);
    k_pool<<<NG, 128, 0, stream>>>(hA, gstart, gend, out);
}

// Round 4
// 778.839 us; speedup vs baseline: 1.3915x; 1.3915x over previous
//
#include <hip/hip_runtime.h>

#define NN 100000
#define NE 1600000
#define HD 128
#define NL 3
#define NG 1024
#define SCAN_B 1024
#define NPART ((NN + SCAN_B - 1) / SCAN_B)   // 98

// ---------------- init ----------------
__global__ void k_init(int* hist, int* gstart, int* gend) {
    int i = blockIdx.x * blockDim.x + threadIdx.x;
    if (i < NN) hist[i] = 0;
    if (i < NG) { gstart[i] = 0x7fffffff; gend[i] = 0; }
}

// ---------------- degree histogram over dst ----------------
__global__ void k_hist(const int* __restrict__ dst, int* __restrict__ hist) {
    int i = blockIdx.x * blockDim.x + threadIdx.x;
    if (i < NE) atomicAdd(&hist[dst[i]], 1);
}

// ---------------- scan phase A: per-block inclusive scan ----------------
__global__ __launch_bounds__(SCAN_B) void k_scan_part(const int* __restrict__ hist,
                                                      int* __restrict__ scanned,
                                                      int* __restrict__ partials) {
    __shared__ int tmp[SCAN_B];
    int b = blockIdx.x, t = threadIdx.x;
    int i = b * SCAN_B + t;
    int v = (i < NN) ? hist[i] : 0;
    tmp[t] = v;
    __syncthreads();
    for (int off = 1; off < SCAN_B; off <<= 1) {
        int u = (t >= off) ? tmp[t - off] : 0;
        __syncthreads();
        tmp[t] += u;
        __syncthreads();
    }
    if (i < NN) scanned[i] = tmp[t];
    if (t == SCAN_B - 1) partials[b] = tmp[t];
}

// ---------------- scan phase B: scan the 98 partials -> exclusive offsets ----------------
__global__ __launch_bounds__(128) void k_scan_part2(const int* __restrict__ partials,
                                                    int* __restrict__ offsets) {
    __shared__ int tmp[128];
    int t = threadIdx.x;
    int v = (t < NPART) ? partials[t] : 0;
    tmp[t] = v;
    __syncthreads();
    for (int off = 1; off < 128; off <<= 1) {
        int u = (t >= off) ? tmp[t - off] : 0;
        __syncthreads();
        tmp[t] += u;
        __syncthreads();
    }
    if (t < NPART) offsets[t] = tmp[t] - v;   // exclusive
}

// ---------------- scan phase C: finalize rowPtr + dinv + cursor (fused) ----------------
__global__ void k_scan_fin(const int* __restrict__ hist, const int* __restrict__ scanned,
                           const int* __restrict__ offsets, int* __restrict__ rowPtr,
                           float* __restrict__ dinv, int* __restrict__ cursor) {
    int i = blockIdx.x * blockDim.x + threadIdx.x;
    if (i >= NN) return;
    int h    = hist[i];
    int incl = scanned[i] + offsets[i >> 10];
    int excl = incl - h;
    rowPtr[i] = excl;
    if (i == NN - 1) rowPtr[NN] = incl;
    dinv[i]   = rsqrtf((float)(h + 1));      // +1 self loop, always > 0
    cursor[i] = excl;
}

// ---------------- CSR fill (group edges by dst) ----------------
__global__ void k_fill(const int* __restrict__ src, const int* __restrict__ dst,
                       const float* __restrict__ dinv, int* __restrict__ cursor,
                       int* __restrict__ srcS, float* __restrict__ normS) {
    int e = blockIdx.x * blockDim.x + threadIdx.x;
    if (e < NE) {
        int s = src[e], d = dst[e];
        int pos = atomicAdd(&cursor[d], 1);
        srcS[pos]  = s;
        normS[pos] = dinv[s] * dinv[d];
    }
}

// ---------------- embedding lookup ----------------
__global__ void k_embed(const int* __restrict__ x, const float* __restrict__ emb,
                        float* __restrict__ h) {
    int i = blockIdx.x * blockDim.x + threadIdx.x;   // over NN*32 float4 slots
    if (i < NN * 32) {
        int n = i >> 5, seg = i & 31;
        const float4* s = (const float4*)(emb + (size_t)x[n] * HD);
        ((float4*)(h + (size_t)n * HD))[seg] = s[seg];
    }
}

// ---------------- GEMM: B = A @ W  (A:[NN,128], W:[128,128]) ----------------
__global__ __launch_bounds__(256) void k_gemm(const float* __restrict__ A,
                                              const float* __restrict__ W,
                                              float* __restrict__ B) {
    __shared__ float As[64][33];     // +1 pad
    __shared__ float Wl[32][128];
    int n0 = blockIdx.x * 64;
    int t = threadIdx.x;
    int cg = t & 15, rg = t >> 4;
    int c0 = cg * 8, r0 = rg * 4;
    float acc[4][8];
#pragma unroll
    for (int i = 0; i < 4; ++i)
#pragma unroll
        for (int j = 0; j < 8; ++j) acc[i][j] = 0.f;

    for (int kc = 0; kc < 4; ++kc) {
        int k0 = kc * 32;
#pragma unroll
        for (int it = 0; it < 2; ++it) {
            int lin = t + it * 256;
            int row = lin >> 3, seg = lin & 7;
            float4 v = make_float4(0.f, 0.f, 0.f, 0.f);
            if (n0 + row < NN)
                v = *(const float4*)(A + (size_t)(n0 + row) * HD + k0 + seg * 4);
            As[row][seg * 4 + 0] = v.x;
            As[row][seg * 4 + 1] = v.y;
            As[row][seg * 4 + 2] = v.z;
            As[row][seg * 4 + 3] = v.w;
        }
#pragma unroll
        for (int it = 0; it < 4; ++it) {
            int lin = t + it * 256;
            int row = lin >> 5, seg = lin & 31;
            *(float4*)(&Wl[row][seg * 4]) =
                *(const float4*)(W + (size_t)(k0 + row) * HD + seg * 4);
        }
        __syncthreads();
#pragma unroll 8
        for (int k = 0; k < 32; ++k) {
            float a0 = As[r0 + 0][k], a1 = As[r0 + 1][k];
            float a2 = As[r0 + 2][k], a3 = As[r0 + 3][k];
            float4 w0 = *(float4*)(&Wl[k][c0]);
            float4 w1 = *(float4*)(&Wl[k][c0 + 4]);
            float w[8] = {w0.x, w0.y, w0.z, w0.w, w1.x, w1.y, w1.z, w1.w};
#pragma unroll
            for (int j = 0; j < 8; ++j) {
                acc[0][j] = fmaf(a0, w[j], acc[0][j]);
                acc[1][j] = fmaf(a1, w[j], acc[1][j]);
                acc[2][j] = fmaf(a2, w[j], acc[2][j]);
                acc[3][j] = fmaf(a3, w[j], acc[3][j]);
            }
        }
        __syncthreads();
    }
#pragma unroll
    for (int i = 0; i < 4; ++i) {
        int row = n0 + r0 + i;
        if (row < NN) {
            float4 o0 = make_float4(acc[i][0], acc[i][1], acc[i][2], acc[i][3]);
            float4 o1 = make_float4(acc[i][4], acc[i][5], acc[i][6], acc[i][7]);
            *(float4*)(B + (size_t)row * HD + c0)     = o0;
            *(float4*)(B + (size_t)row * HD + c0 + 4) = o1;
        }
    }
}

// ---------------- pull-gather: A[n] = sum_e norm*B[src] + dinv^2*B[n] + b ----------------
__global__ __launch_bounds__(256) void k_gather(const float* __restrict__ B,
                                                const int* __restrict__ rowPtr,
                                                const int* __restrict__ srcS,
                                                const float* __restrict__ normS,
                                                const float* __restrict__ dinv,
                                                const float* __restrict__ bias,
                                                float* __restrict__ A, int relu) {
    int wid  = (blockIdx.x * blockDim.x + threadIdx.x) >> 6;  // wave per node
    int lane = threadIdx.x & 63;
    if (wid >= NN) return;
    int n = wid;
    float dn = dinv[n];
    float2 b0 = ((const float2*)(B + (size_t)n * HD))[lane];
    float2 acc;
    acc.x = dn * dn * b0.x;
    acc.y = dn * dn * b0.y;
    int beg = rowPtr[n], end = rowPtr[n + 1];
    int idx = beg;
    // 4-wide unroll: 4 outstanding feature-row loads per wave
    for (; idx + 4 <= end; idx += 4) {
        int   s0 = srcS[idx],     s1 = srcS[idx + 1];
        int   s2 = srcS[idx + 2], s3 = srcS[idx + 3];
        float w0 = normS[idx],     w1 = normS[idx + 1];
        float w2 = normS[idx + 2], w3 = normS[idx + 3];
        float2 v0 = ((const float2*)(B + (size_t)s0 * HD))[lane];
        float2 v1 = ((const float2*)(B + (size_t)s1 * HD))[lane];
        float2 v2 = ((const float2*)(B + (size_t)s2 * HD))[lane];
        float2 v3 = ((const float2*)(B + (size_t)s3 * HD))[lane];
        acc.x = fmaf(w0, v0.x, acc.x); acc.y = fmaf(w0, v0.y, acc.y);
        acc.x = fmaf(w1, v1.x, acc.x); acc.y = fmaf(w1, v1.y, acc.y);
        acc.x = fmaf(w2, v2.x, acc.x); acc.y = fmaf(w2, v2.y, acc.y);
        acc.x = fmaf(w3, v3.x, acc.x); acc.y = fmaf(w3, v3.y, acc.y);
    }
    for (; idx < end; ++idx) {
        int s   = srcS[idx];
        float w = normS[idx];
        float2 v = ((const float2*)(B + (size_t)s * HD))[lane];
        acc.x = fmaf(w, v.x, acc.x);
        acc.y = fmaf(w, v.y, acc.y);
    }
    float2 bb = ((const float2*)bias)[lane];
    acc.x += bb.x;
    acc.y += bb.y;
    if (relu) { acc.x = fmaxf(acc.x, 0.f); acc.y = fmaxf(acc.y, 0.f); }
    ((float2*)(A + (size_t)n * HD))[lane] = acc;
}

// ---------------- graph bounds (batch is sorted) ----------------
__global__ void k_bounds(const int* __restrict__ batch, int* __restrict__ gstart,
                         int* __restrict__ gend) {
    int i = blockIdx.x * blockDim.x + threadIdx.x;
    if (i < NN) {
        int g = batch[i];
        atomicMin(&gstart[g], i);
        atomicMax(&gend[g], i + 1);
    }
}

// ---------------- mean pool per graph ----------------
__global__ __launch_bounds__(128) void k_pool(const float* __restrict__ A,
                                              const int* __restrict__ gstart,
                                              const int* __restrict__ gend,
                                              float* __restrict__ out) {
    int g = blockIdx.x;
    int t = threadIdx.x;
    int s = gstart[g], e = gend[g];
    float acc = 0.f;
    int cnt = 0;
    if (s < e) {
        cnt = e - s;
        for (int n = s; n < e; ++n) acc += A[(size_t)n * HD + t];
    }
    out[(size_t)g * HD + t] = acc / fmaxf((float)cnt, 1.f);
}

extern "C" void kernel_launch(void* const* d_in, const int* in_sizes, int n_in,
                              void* d_out, int out_size, void* d_ws, size_t ws_size,
                              hipStream_t stream) {
    const int*   x     = (const int*)d_in[0];
    const int*   ei    = (const int*)d_in[1];
    const int*   batch = (const int*)d_in[2];
    const float* emb   = (const float*)d_in[3];
    const float* Ws    = (const float*)d_in[4];
    const float* bs    = (const float*)d_in[5];
    float* out = (float*)d_out;

    const int* srcE = ei;
    const int* dstE = ei + NE;

    char* ws = (char*)d_ws;
    size_t off = 0;
    auto alloc = [&](size_t bytes) {
        size_t o = off;
        off = (off + bytes + 255) & ~(size_t)255;
        return o;
    };
    float* hA      = (float*)(ws + alloc((size_t)NN * HD * 4));
    float* hB      = (float*)(ws + alloc((size_t)NN * HD * 4));
    float* dinv    = (float*)(ws + alloc((size_t)NN * 4));
    int*   rowPtr  = (int*)  (ws + alloc((size_t)(NN + 1) * 4));
    int*   cursor  = (int*)  (ws + alloc((size_t)NN * 4));   // aliases hist
    int*   scanned = (int*)  (ws + alloc((size_t)NN * 4));
    int*   parts   = (int*)  (ws + alloc((size_t)NPART * 4));
    int*   offs    = (int*)  (ws + alloc((size_t)NPART * 4));
    int*   srcS    = (int*)  (ws + alloc((size_t)NE * 4));
    float* normS   = (float*)(ws + alloc((size_t)NE * 4));
    int*   gstart  = (int*)  (ws + alloc((size_t)NG * 4));
    int*   gend    = (int*)  (ws + alloc((size_t)NG * 4));
    (void)ws_size; (void)in_sizes; (void)n_in; (void)out_size;

    int* hist = cursor;  // reuse: hist phase then cursor phase

    k_init<<<(NN + 255) / 256, 256, 0, stream>>>(hist, gstart, gend);
    k_hist<<<(NE + 255) / 256, 256, 0, stream>>>(dstE, hist);
    k_scan_part<<<NPART, SCAN_B, 0, stream>>>(hist, scanned, parts);
    k_scan_part2<<<1, 128, 0, stream>>>(parts, offs);
    k_scan_fin<<<(NN + 255) / 256, 256, 0, stream>>>(hist, scanned, offs, rowPtr, dinv, cursor);
    k_fill<<<(NE + 255) / 256, 256, 0, stream>>>(srcE, dstE, dinv, cursor, srcS, normS);
    k_embed<<<(NN * 32 + 255) / 256, 256, 0, stream>>>(x, emb, hA);

    for (int l = 0; l < NL; ++l) {
        k_gemm<<<(NN + 63) / 64, 256, 0, stream>>>(hA, Ws + (size_t)l * HD * HD, hB);
        k_gather<<<(NN + 3) / 4, 256, 0, stream>>>(hB, rowPtr, srcS, normS, dinv,
                                                   bs + (size_t)l * HD, hA,
                                                   (l < NL - 1) ? 1 : 0);
    }

    k_bounds<<<(NN + 255) / 256, 256, 0, stream>>>(batch, gstart, gend);
    k_pool<<<NG, 128, 0, stream>>>(hA, gstart, gend, out);
}